// Round 4
// baseline (190.797 us; speedup 1.0000x reference)
//
#include <hip/hip_runtime.h>
#include <hip/hip_bf16.h>

// CompanyOperationEvaluation R13: 64 rows/block, 256 blocks x 512 threads.
//  Halves the per-CU weight-broadcast request stream (1 block/CU stages each
//  16KB weight tile once, vs 2 blocks in R12) -- the theory is L2 request
//  congestion drives the ~2200cyc/step stall. Per-SIMD wave count unchanged
//  (8 waves/CU). gemm_phase schedule identical to R12 (proven): 3-deep reg
//  ring, LDS double-buffer, 1 raw barrier/step, 8 MFMAs/wave/step.
//  Wave layout: 8 waves = wm(2) x wn(4); wave covers 32 rows x 32 cols.
//  LDS: regionA 68.6KB (feat 64x264 | buf0/1 64x136; x0_sh 64x520 aliases)
//       + b_sh 36.9KB + w2 4KB + cw 2KB = 111.6KB -> 1 block/CU.
// Lesson bank: (R2/R6) gather off the MFMA critical path (issue-early);
// (R5) >=8 MFMAs/wave/step; (R10) fusion needs load pipelining; (R11) raw
// barrier keeps prefetch in flight; (R12) 3-deep ring + fused gather good.

typedef __bf16 bf16x8 __attribute__((ext_vector_type(8)));
typedef float floatx4 __attribute__((ext_vector_type(4)));

__device__ __forceinline__ unsigned short f2bf(float x) {
  unsigned int u = __builtin_bit_cast(unsigned int, x);
  u = (u + 0x7FFFu + ((u >> 16) & 1u)) >> 16;
  return (unsigned short)u;
}

#define PHASE_BAR()                                      \
  do {                                                   \
    asm volatile("s_waitcnt lgkmcnt(0)" ::: "memory");   \
    __builtin_amdgcn_s_barrier();                        \
    __builtin_amdgcn_sched_barrier(0);                   \
  } while (0)

// ---------------------------------------------------------------------------
// K1 prep: blocks [0,304) 32x32 transpose tiles; block 304 W2.
// ---------------------------------------------------------------------------
__global__ __launch_bounds__(256) void prep_kernel(
    const float* __restrict__ Wf, const float* __restrict__ Wu,
    const float* __restrict__ W0, const float* __restrict__ W1,
    const float* __restrict__ W2,
    unsigned short* __restrict__ wfT, unsigned short* __restrict__ wuT,
    unsigned short* __restrict__ w0T, unsigned short* __restrict__ w1T,
    unsigned short* __restrict__ w2T) {
  __shared__ unsigned short tile[32][34];
  const int bid = blockIdx.x, tid = threadIdx.x;
  if (bid < 304) {
    int t = bid;
    const float* src; unsigned short* dst; int N, K, kt, nt;
    if (t < 32)       { src = Wf; dst = wfT; N = 128; K = 256; kt = t >> 2;       nt = t & 3; }
    else if (t < 48)  { t -= 32;  src = Wu; dst = wuT; N = 128; K = 128; kt = t >> 2; nt = t & 3; }
    else if (t < 176) { t -= 48;  src = W0; dst = w0T; N = 512; K = 256; kt = t >> 4; nt = t & 15; }
    else              { t -= 176; src = W1; dst = w1T; N = 256; K = 512; kt = t >> 3; nt = t & 7; }
    {
      int r = tid >> 3, cg = (tid & 7) * 4;
      float4 v = *(const float4*)(src + (size_t)(kt * 32 + r) * N + nt * 32 + cg);
      tile[r][cg + 0] = f2bf(v.x); tile[r][cg + 1] = f2bf(v.y);
      tile[r][cg + 2] = f2bf(v.z); tile[r][cg + 3] = f2bf(v.w);
    }
    __syncthreads();
    {
      int rp = tid >> 3, cg = (tid & 7) * 4;
      uint2 o;
      o.x = (unsigned)tile[cg + 0][rp] | ((unsigned)tile[cg + 1][rp] << 16);
      o.y = (unsigned)tile[cg + 2][rp] | ((unsigned)tile[cg + 3][rp] << 16);
      *(uint2*)(dst + (size_t)(nt * 32 + rp) * K + kt * 32 + cg) = o;
    }
  } else {
#pragma unroll
    for (int i = 0; i < 8; ++i) {
      int g = tid * 8 + i, k = g >> 3, n = g & 7;
      w2T[n * 256 + k] = f2bf(W2[g]);
    }
  }
}

// ---------------------------------------------------------------------------
// Pipelined phase helpers (512-thread block).
// B tile per step: 128 n-rows x 64 k, staged reg->LDS (2 uint4/thread).
// ---------------------------------------------------------------------------
template <int LDK>
__device__ __forceinline__ void loadB(uint4 (&r)[2],
                                      const unsigned short* __restrict__ p,
                                      int tid) {
#pragma unroll
  for (int i = 0; i < 2; ++i) {
    int chunk = i * 512 + tid, row = chunk >> 3, seg = chunk & 7;
    r[i] = *(const uint4*)(p + (size_t)row * LDK + seg * 8);
  }
}

__device__ __forceinline__ void dsw(unsigned short* b, const uint4 (&r)[2],
                                    int tid) {
#pragma unroll
  for (int i = 0; i < 2; ++i) {
    int chunk = i * 512 + tid, row = chunk >> 3, seg = chunk & 7;
    *(uint4*)&b[row * 72 + seg * 8] = r[i];
  }
}

template <int PASS_STEPS, int LDK>
__device__ __forceinline__ const unsigned short* srcstep(
    const unsigned short* __restrict__ s, int st) {
  return s + (size_t)(st / PASS_STEPS) * 128 * LDK + (st % PASS_STEPS) * 64;
}

// One K-step of MFMAs: wave covers 32 rows x 32 cols, acc[4] = [mi*2+ni].
template <int LDA>
__device__ __forceinline__ void mstep(const unsigned short* A,
                                      const unsigned short* b, int k0,
                                      floatx4* acc, int m16, int quad,
                                      int wm, int wn) {
#pragma unroll
  for (int kk = 0; kk < 64; kk += 32) {
    bf16x8 a0 = *(const bf16x8*)&A[(wm * 32 + m16) * LDA + k0 + kk + quad * 8];
    bf16x8 a1 = *(const bf16x8*)&A[(wm * 32 + 16 + m16) * LDA + k0 + kk + quad * 8];
    bf16x8 b0 = *(const bf16x8*)&b[(wn * 32 + m16) * 72 + kk + quad * 8];
    bf16x8 b1 = *(const bf16x8*)&b[(wn * 32 + 16 + m16) * 72 + kk + quad * 8];
    acc[0] = __builtin_amdgcn_mfma_f32_16x16x32_bf16(a0, b0, acc[0], 0, 0, 0);
    acc[1] = __builtin_amdgcn_mfma_f32_16x16x32_bf16(a0, b1, acc[1], 0, 0, 0);
    acc[2] = __builtin_amdgcn_mfma_f32_16x16x32_bf16(a1, b0, acc[2], 0, 0, 0);
    acc[3] = __builtin_amdgcn_mfma_f32_16x16x32_bf16(a1, b1, acc[3], 0, 0, 0);
  }
}

// Full pipelined phase: T K-steps (PASS_STEPS per n-pass), 1 barrier/step,
// 3-deep register ring (2 K-steps of load lookahead).
template <int T, int LDA, int PASS_STEPS, int LDK>
__device__ __forceinline__ void gemm_phase(
    const unsigned short* A, const unsigned short* __restrict__ src,
    unsigned short* b_sh, floatx4* acc, int tid, int m16, int quad, int wm,
    int wn) {
  uint4 r[3][2];
  loadB<LDK>(r[0], srcstep<PASS_STEPS, LDK>(src, 0), tid);
  dsw(b_sh, r[0], tid);
  if (T > 1) loadB<LDK>(r[1], srcstep<PASS_STEPS, LDK>(src, 1), tid);
  if (T > 2) loadB<LDK>(r[2], srcstep<PASS_STEPS, LDK>(src, 2), tid);
  PHASE_BAR();
#pragma unroll
  for (int t = 0; t < T; ++t) {
    if (t + 3 < T)
      loadB<LDK>(r[t % 3], srcstep<PASS_STEPS, LDK>(src, t + 3), tid);
    mstep<LDA>(A, b_sh + (t & 1) * 9216, (t % PASS_STEPS) * 64,
               acc + (t / PASS_STEPS) * 4, m16, quad, wm, wn);
    if (t + 1 < T) dsw(b_sh + ((t + 1) & 1) * 9216, r[(t + 1) % 3], tid);
    PHASE_BAR();
  }
}

// ---------------------------------------------------------------------------
// K2 fused_mlp: 256 blocks x 64 rows x 512 threads.
// ---------------------------------------------------------------------------
__global__ __launch_bounds__(512, 2) void fused_mlp_kernel(
    const float* __restrict__ features, const int* __restrict__ ent_idx,
    const float* __restrict__ head_tab, const float* __restrict__ ent_tab,
    const float* __restrict__ w_cf, const float* __restrict__ w_fc,
    const float* __restrict__ w_ef, const float* __restrict__ w_fe,
    const float* __restrict__ b_c, const float* __restrict__ b_e,
    const unsigned short* __restrict__ wfT,
    const unsigned short* __restrict__ wuT, const float* __restrict__ bf_,
    const float* __restrict__ bu,
    const unsigned short* __restrict__ w0T, const float* __restrict__ b0,
    const unsigned short* __restrict__ w1T, const float* __restrict__ b1,
    const unsigned short* __restrict__ w2T, const float* __restrict__ b2,
    const int* __restrict__ target, float* __restrict__ out) {
  // regionA (shorts): [0,16896) feat/A_sh 64x264; [16896,25600) buf0 64x136;
  // [25600,34304) buf1 64x136. x0_sh 64x520 = 33280 aliases [0,33280).
  __shared__ __align__(16) unsigned short regionA[34304];   // 68.6 KB
  __shared__ __align__(16) unsigned short b_sh[2 * 9216];   // 36.9 KB
  __shared__ __align__(16) unsigned short w2_sh[2048];      //  4.0 KB
  __shared__ __align__(16) float cw_sh[512];                //  2.0 KB
  unsigned short* feat_sh = regionA;
  unsigned short* buf0 = regionA + 16896;
  unsigned short* buf1 = regionA + 25600;
  unsigned short* A_sh = regionA;   // 64x264: [cf2 | e] concat
  unsigned short* x0_sh = regionA;  // 64x520
  unsigned short* x1_sh = b_sh;     // 64x264 = 16896 <= 18432

  const int tid = threadIdx.x;
  const int r0 = blockIdx.x * 64;
  const int lane = tid & 63, wave = tid >> 6;
  const int m16 = lane & 15, quad = lane >> 4;
  const int wm = wave >> 2, wn = wave & 3;

  // ---- gather issue (earliest point; consumed after L1) ----
  // 8 lanes/row, 64 rows, 16 fp32/lane per table.
  const int grow = tid >> 3, gpart = tid & 7;
  const int gidx = ent_idx[r0 + grow];
  const float* hp = head_tab + (size_t)gidx * 128 + gpart * 16;
  const float* ep = ent_tab + (size_t)gidx * 128 + gpart * 16;
  float4 h4[4], e4[4];
#pragma unroll
  for (int j = 0; j < 4; ++j) {
    h4[j] = *(const float4*)(hp + j * 4);
    e4[j] = *(const float4*)(ep + j * 4);
  }
  // cross weights -> LDS (read at cross time, behind L1's barriers)
  if (tid < 128) {
    int a = tid >> 5, o = (tid & 31) * 4;
    const float* s = (a == 0) ? w_cf : (a == 1) ? w_fc : (a == 2) ? w_ef : w_fe;
    *(float4*)&cw_sh[a * 128 + o] = *(const float4*)(s + o);
  }
  if (tid < 256) *(uint4*)&w2_sh[tid * 8] = *(const uint4*)(w2T + tid * 8);

  // stage features fp32->bf16: 64 rows x 64 float4 = 4096, 8/thread
#pragma unroll
  for (int i = 0; i < 8; ++i) {
    int idx4 = i * 512 + tid;
    int row = idx4 >> 6, c = (idx4 & 63) * 4;
    float4 v = *(const float4*)(features + (size_t)(r0 + row) * 256 + c);
    uint2 o;
    o.x = (unsigned)f2bf(v.x) | ((unsigned)f2bf(v.y) << 16);
    o.y = (unsigned)f2bf(v.z) | ((unsigned)f2bf(v.w) << 16);
    *(uint2*)&feat_sh[row * 264 + c] = o;
  }

  floatx4 acc[4];
  // ---- L1: cf0 = relu(feat @ Wf + bf), K=256, N=128 ----
#pragma unroll
  for (int j = 0; j < 4; ++j) acc[j] = (floatx4){0.f, 0.f, 0.f, 0.f};
  gemm_phase<4, 264, 4, 256>(feat_sh, wfT, b_sh, acc, tid, m16, quad, wm, wn);
#pragma unroll
  for (int mi = 0; mi < 2; ++mi)
#pragma unroll
    for (int ni = 0; ni < 2; ++ni) {
      int col = wn * 32 + ni * 16 + m16;
      float bv = bf_[col];
#pragma unroll
      for (int r = 0; r < 4; ++r)
        buf0[(wm * 32 + mi * 16 + quad * 4 + r) * 136 + col] =
            f2bf(fmaxf(acc[mi * 2 + ni][r] + bv, 0.f));
    }

  // ---- cross_compress x2 (consume gather) -> A_sh[:,128:256] ----
  {
    float h[16], e[16];
#pragma unroll
    for (int j = 0; j < 4; ++j) {
      h[4 * j + 0] = h4[j].x; h[4 * j + 1] = h4[j].y;
      h[4 * j + 2] = h4[j].z; h[4 * j + 3] = h4[j].w;
      e[4 * j + 0] = e4[j].x; e[4 * j + 1] = e4[j].y;
      e[4 * j + 2] = e4[j].z; e[4 * j + 3] = e4[j].w;
    }
    const float bc = b_c[0], be = b_e[0];
#pragma unroll
    for (int it = 0; it < 2; ++it) {
      float d0 = 0.f, d1 = 0.f, d2 = 0.f, d3 = 0.f;
#pragma unroll
      for (int j = 0; j < 16; ++j) {
        float wcf = cw_sh[0 * 128 + gpart * 16 + j];
        float wfc = cw_sh[1 * 128 + gpart * 16 + j];
        float wef = cw_sh[2 * 128 + gpart * 16 + j];
        float wfe = cw_sh[3 * 128 + gpart * 16 + j];
        d0 += e[j] * wcf; d1 += h[j] * wfc;
        d2 += e[j] * wef; d3 += h[j] * wfe;
      }
#pragma unroll
      for (int s = 1; s < 8; s <<= 1) {
        d0 += __shfl_xor(d0, s); d1 += __shfl_xor(d1, s);
        d2 += __shfl_xor(d2, s); d3 += __shfl_xor(d3, s);
      }
#pragma unroll
      for (int j = 0; j < 16; ++j) {
        float nh = h[j] * d0 + e[j] * d1 + bc;
        float ne = h[j] * d2 + e[j] * d3 + be;
        h[j] = nh; e[j] = ne;
      }
    }
    uint4 o0, o1;
    unsigned* w = (unsigned*)&o0;
#pragma unroll
    for (int j = 0; j < 4; ++j)
      w[j] = (unsigned)f2bf(e[2 * j]) | ((unsigned)f2bf(e[2 * j + 1]) << 16);
    w = (unsigned*)&o1;
#pragma unroll
    for (int j = 0; j < 4; ++j)
      w[j] = (unsigned)f2bf(e[8 + 2 * j]) |
             ((unsigned)f2bf(e[8 + 2 * j + 1]) << 16);
    *(uint4*)&A_sh[grow * 264 + 128 + gpart * 16] = o0;
    *(uint4*)&A_sh[grow * 264 + 128 + gpart * 16 + 8] = o1;
  }

  // ---- L2: cf1 = relu(cf0 @ Wu + bu), K=128, N=128 ----
#pragma unroll
  for (int j = 0; j < 4; ++j) acc[j] = (floatx4){0.f, 0.f, 0.f, 0.f};
  gemm_phase<2, 136, 2, 128>(buf0, wuT, b_sh, acc, tid, m16, quad, wm, wn);
#pragma unroll
  for (int mi = 0; mi < 2; ++mi)
#pragma unroll
    for (int ni = 0; ni < 2; ++ni) {
      int col = wn * 32 + ni * 16 + m16;
      float bv = bu[col];
#pragma unroll
      for (int r = 0; r < 4; ++r)
        buf1[(wm * 32 + mi * 16 + quad * 4 + r) * 136 + col] =
            f2bf(fmaxf(acc[mi * 2 + ni][r] + bv, 0.f));
    }

  // ---- L3: cf2 = relu(cf1 @ Wu + bu) -> A_sh[:,0:128] ----
  // b_sh halves still hold wuT steps 0,1 from L2: zero staging.
#pragma unroll
  for (int j = 0; j < 4; ++j) acc[j] = (floatx4){0.f, 0.f, 0.f, 0.f};
  PHASE_BAR();  // buf1 (L2 epilogue ds_writes) visible to all waves
  mstep<136>(buf1, b_sh, 0, acc, m16, quad, wm, wn);
  mstep<136>(buf1, b_sh + 9216, 64, acc, m16, quad, wm, wn);
  PHASE_BAR();  // drain b_sh ds_reads before x0 prologue overwrites b_sh
#pragma unroll
  for (int mi = 0; mi < 2; ++mi)
#pragma unroll
    for (int ni = 0; ni < 2; ++ni) {
      int col = wn * 32 + ni * 16 + m16;
      float bv = bu[col];
#pragma unroll
      for (int r = 0; r < 4; ++r)
        A_sh[(wm * 32 + mi * 16 + quad * 4 + r) * 264 + col] =
            f2bf(fmaxf(acc[mi * 2 + ni][r] + bv, 0.f));
    }

  // ---- x0 = relu(A @ W0 + b0), K=256, N=512 as 4 n-passes ----
  floatx4 acc16[16];
#pragma unroll
  for (int j = 0; j < 16; ++j) acc16[j] = (floatx4){0.f, 0.f, 0.f, 0.f};
  gemm_phase<16, 264, 4, 256>(A_sh, w0T, b_sh, acc16, tid, m16, quad, wm, wn);
#pragma unroll
  for (int np = 0; np < 4; ++np)
#pragma unroll
    for (int mi = 0; mi < 2; ++mi)
#pragma unroll
      for (int ni = 0; ni < 2; ++ni) {
        int col = np * 128 + wn * 32 + ni * 16 + m16;
        float bv = b0[col];
#pragma unroll
        for (int r = 0; r < 4; ++r)
          x0_sh[(wm * 32 + mi * 16 + quad * 4 + r) * 520 + col] =
              f2bf(fmaxf(acc16[np * 4 + mi * 2 + ni][r] + bv, 0.f));
      }

  // ---- x1 = relu(x0 @ W1 + b1), K=512, N=256 as 2 n-passes ----
  floatx4 acc8[8];
#pragma unroll
  for (int j = 0; j < 8; ++j) acc8[j] = (floatx4){0.f, 0.f, 0.f, 0.f};
  gemm_phase<16, 520, 8, 512>(x0_sh, w1T, b_sh, acc8, tid, m16, quad, wm, wn);
#pragma unroll
  for (int np = 0; np < 2; ++np)
#pragma unroll
    for (int mi = 0; mi < 2; ++mi)
#pragma unroll
      for (int ni = 0; ni < 2; ++ni) {
        int col = np * 128 + wn * 32 + ni * 16 + m16;
        float bv = b1[col];
#pragma unroll
        for (int r = 0; r < 4; ++r)
          x1_sh[(wm * 32 + mi * 16 + quad * 4 + r) * 264 + col] =
              f2bf(fmaxf(acc8[np * 4 + mi * 2 + ni][r] + bv, 0.f));
      }
  PHASE_BAR();

  // W2 GEMV + softmax: 8 lanes/row, 64 rows, 32 elems/lane
  {
    int row = tid >> 3, q = tid & 7;
    float p[8];
#pragma unroll
    for (int n = 0; n < 8; ++n) p[n] = 0.f;
#pragma unroll
    for (int jb = 0; jb < 4; ++jb) {
      bf16x8 xv = *(const bf16x8*)&x1_sh[row * 264 + q * 32 + jb * 8];
#pragma unroll
      for (int n = 0; n < 8; ++n) {
        bf16x8 wv = *(const bf16x8*)&w2_sh[n * 256 + q * 32 + jb * 8];
#pragma unroll
        for (int j = 0; j < 8; ++j) p[n] += (float)xv[j] * (float)wv[j];
      }
    }
#pragma unroll
    for (int s = 1; s < 8; s <<= 1)
#pragma unroll
      for (int n = 0; n < 8; ++n) p[n] += __shfl_xor(p[n], s);
    if (q == 0) {
      float mx = -1e30f;
#pragma unroll
      for (int n = 0; n < 8; ++n) {
        p[n] = fmaxf(p[n] + b2[n], 0.f);
        mx = fmaxf(mx, p[n]);
      }
      float sum = 0.f;
#pragma unroll
      for (int n = 0; n < 8; ++n) { p[n] = __expf(p[n] - mx); sum += p[n]; }
      const float inv = 1.f / sum;
      const int gr = r0 + row;
      float4 o0 = {p[0] * inv, p[1] * inv, p[2] * inv, p[3] * inv};
      float4 o1 = {p[4] * inv, p[5] * inv, p[6] * inv, p[7] * inv};
      *(float4*)(out + (size_t)gr * 8) = o0;
      *(float4*)(out + (size_t)gr * 8 + 4) = o1;
      out[16384 * 8 + gr] = (float)target[gr];
    }
  }
}

extern "C" void kernel_launch(void* const* d_in, const int* in_sizes, int n_in,
                              void* d_out, int out_size, void* d_ws, size_t ws_size,
                              hipStream_t stream) {
  const float* features = (const float*)d_in[0];
  const int* ent_idx    = (const int*)d_in[1];
  const int* target     = (const int*)d_in[2];
  const float* Wf  = (const float*)d_in[3];
  const float* bf_ = (const float*)d_in[4];
  const float* Wu  = (const float*)d_in[5];
  const float* bu  = (const float*)d_in[6];
  const float* w_cf = (const float*)d_in[7];
  const float* w_fc = (const float*)d_in[8];
  const float* w_ef = (const float*)d_in[9];
  const float* w_fe = (const float*)d_in[10];
  const float* b_c  = (const float*)d_in[11];
  const float* b_e  = (const float*)d_in[12];
  const float* head_tab = (const float*)d_in[13];
  const float* ent_tab  = (const float*)d_in[14];
  const float* W0 = (const float*)d_in[15];
  const float* b0 = (const float*)d_in[16];
  const float* W1 = (const float*)d_in[17];
  const float* b1 = (const float*)d_in[18];
  const float* W2 = (const float*)d_in[19];
  const float* b2 = (const float*)d_in[20];
  float* out = (float*)d_out;

  unsigned short* ws = (unsigned short*)d_ws;
  size_t off = 0;
  auto alloc = [&](size_t n) { unsigned short* p = ws + off; off += n; return p; };
  unsigned short* wfT  = alloc(32768);
  unsigned short* wuT  = alloc(16384);
  unsigned short* w0T  = alloc(131072);
  unsigned short* w1T  = alloc(131072);
  unsigned short* w2T  = alloc(2048);
  (void)ws_size; (void)in_sizes; (void)n_in; (void)out_size;

  // K1: weight transposes only
  prep_kernel<<<305, 256, 0, stream>>>(Wf, Wu, W0, W1, W2,
                                       wfT, wuT, w0T, w1T, w2T);
  // K2: full fused per-row pipeline, 64 rows/block
  fused_mlp_kernel<<<256, 512, 0, stream>>>(features, ent_idx, head_tab,
      ent_tab, w_cf, w_fc, w_ef, w_fe, b_c, b_e, wfT, wuT, bf_, bu,
      w0T, b0, w1T, b1, w2T, b2, target, out);
}